// Round 13
// baseline (748.116 us; speedup 1.0000x reference)
//
#include <hip/hip_runtime.h>
#include <cstdint>
#include <cstddef>

#define T_   4
#define NTOK 2048
#define D_   1024
#define EF   512
#define NE   8
#define TP   8   // (token,expert) pairs per tile -> 32 rows = 2 MFMA row-groups

typedef __attribute__((ext_vector_type(4))) double d4;

// ---------------- ws layout ----------------
#define WS_RP    0        // double[NTOK*NE]                     131072 B
#define WS_CNT   131072   // int[NE]                             32 B
#define WS_LTOK  131104   // int[NE*NTOK]                        65536 B
#define WS_LW    196640   // double[NE*NTOK]                     131072 B
#define WS_GMASK 327712   // ushort[NE*2048*4][32]  spike bits   4 MiB

// ---------------------------------------------------------------------------
// Kernel 1: routing (unchanged — verified exact, absmax 0.0)
// ---------------------------------------------------------------------------
__global__ __launch_bounds__(256) void moe_routing(
    const float* __restrict__ x, const float* __restrict__ bias,
    double* __restrict__ rp, int* __restrict__ cnt,
    int* __restrict__ ltok, double* __restrict__ lw)
{
    const int n   = blockIdx.x;
    const int tid = threadIdx.x;
    __shared__ int scnt[NE];
    if (tid < NE) scnt[tid] = 0;
    __syncthreads();

    int c = 0;
#pragma unroll
    for (int j = 0; j < 4; ++j) {
        const int d = j * 256 + tid;
        double v = 0.0;
#pragma unroll
        for (int t = 0; t < T_; ++t) {
            v = 0.9 * v + (double)x[((size_t)t * NTOK + n) * D_ + d];
            if (v - 1.0 >= 0.0) { ++c; v -= 1.0; }
        }
    }
    c += __shfl_xor(c, 1);
    c += __shfl_xor(c, 2);
    c += __shfl_xor(c, 4);
    if ((tid & 7) == 0) atomicAdd(&scnt[(tid >> 3) & 7], c);
    __syncthreads();

    if (tid == 0) {
        double es[NE];
#pragma unroll
        for (int e = 0; e < NE; ++e)
            es[e] = (double)scnt[e] * (1.0 / 512.0) + (double)bias[e];

        int i0 = 0; double b0 = es[0];
        for (int e = 1; e < NE; ++e) if (es[e] > b0) { b0 = es[e]; i0 = e; }
        int i1 = -1; double b1 = -1e300;
        for (int e = 0; e < NE; ++e) if (e != i0 && es[e] > b1) { b1 = es[e]; i1 = e; }

        const double e1 = exp(b1 - b0);
        const double w0 = 1.0 / (1.0 + e1);
        const double w1 = e1 / (1.0 + e1);

        double mx = es[0];
        for (int e = 1; e < NE; ++e) mx = es[e] > mx ? es[e] : mx;
        double s = 0.0, ex[NE];
        for (int e = 0; e < NE; ++e) { ex[e] = exp(es[e] - mx); s += ex[e]; }
        for (int e = 0; e < NE; ++e) rp[(size_t)n * NE + e] = ex[e] / s;

        int s0 = atomicAdd(&cnt[i0], 1);
        ltok[i0 * NTOK + s0] = n; lw[i0 * NTOK + s0] = w0;
        int s1 = atomicAdd(&cnt[i1], 1);
        ltok[i1 * NTOK + s1] = n; lw[i1 * NTOK + s1] = w1;
    }
}

// ---------------------------------------------------------------------------
// Kernel 2: load-balance loss (unchanged)
// ---------------------------------------------------------------------------
__global__ __launch_bounds__(256) void moe_finalize(
    const double* __restrict__ rp, const int* __restrict__ cnt,
    float* __restrict__ out_lb)
{
    __shared__ double red[256][NE];
    const int tid = threadIdx.x;
    double a[NE];
#pragma unroll
    for (int e = 0; e < NE; ++e) a[e] = 0.0;
    for (int n = tid; n < NTOK; n += 256)
#pragma unroll
        for (int e = 0; e < NE; ++e) a[e] += rp[(size_t)n * NE + e];
#pragma unroll
    for (int e = 0; e < NE; ++e) red[tid][e] = a[e];
    __syncthreads();
    if (tid < NE) {
        double s = 0.0;
        for (int i = 0; i < 256; ++i) s += red[i][tid];
        red[0][tid] = s;
    }
    __syncthreads();
    if (tid == 0) {
        double lb = 0.0;
#pragma unroll
        for (int e = 0; e < NE; ++e)
            lb += ((double)cnt[e] / (double)(NTOK * 2)) * (red[0][e] / (double)NTOK);
        out_lb[0] = (float)(8.0 * lb);
    }
}

// probe decode (verified on HW in R5): fam0 lane=16k+idx -> val=96+4idx;
// fam1 lane=4idx+k -> val=6+16idx.
__device__ __forceinline__ int dec_idx(double val, int* fam) {
    const double r0 = (val - 96.0) * 0.25;
    const int i0 = (int)r0;
    if ((double)i0 == r0 && i0 >= 0 && i0 < 16) { *fam = 0; return i0; }
    const double r1 = (val - 6.0) * 0.0625;
    const int i1 = (int)r1;
    if ((double)i1 == r1 && i1 >= 0 && i1 < 16) { *fam = 1; return i1; }
    *fam = -1; return 0;
}

struct Frag {
    int vA, kA, uB, kB;   // A-row / A-k / B-col / B-k index of this lane
    int vC[4], uC[4];     // D (row,col) of acc reg r
    int bad;
};

__device__ __forceinline__ Frag probe_layout(int l) {
    Frag fr; fr.bad = 0;
    const d4 zz = {0.0, 0.0, 0.0, 0.0};
    const double dl = (double)l;
    const d4 Dv = __builtin_amdgcn_mfma_f64_16x16x4f64(dl, 1.0, zz, 0, 0, 0);
    const d4 Du = __builtin_amdgcn_mfma_f64_16x16x4f64(1.0, dl, zz, 0, 0, 0);
    int famA = -1, famB = -1;
#pragma unroll
    for (int r = 0; r < 4; ++r) {
        int fa, fb;
        fr.vC[r] = dec_idx(Dv[r], &fa);
        fr.uC[r] = dec_idx(Du[r], &fb);
        if (r == 0) { famA = fa; famB = fb; }
        fr.bad |= (fa != famA) | (fb != famB) | (fa < 0) | (fb < 0);
    }
    fr.vA = (famA == 0) ? (l & 15) : (l >> 2);
    fr.kA = (famA == 0) ? (l >> 4) : (l & 3);
    fr.uB = (famB == 0) ? (l & 15) : (l >> 2);
    fr.kB = (famB == 0) ? (l >> 4) : (l & 3);
    const d4 D3 = __builtin_amdgcn_mfma_f64_16x16x4f64(
        (double)(1 << fr.kA), (double)(16 << fr.kB), zz, 0, 0, 0);
#pragma unroll
    for (int r = 0; r < 4; ++r) fr.bad |= (D3[r] != 1360.0);
    return fr;
}

// gmask row of 32 ushorts per (e, pairIdx, t)
__device__ __forceinline__ size_t gm_row(int e, int pairIdx, int t) {
    return ((size_t)((e << 11) + pairIdx) * 4 + t) * 32;
}

// ---------------------------------------------------------------------------
// Kernel 3a: up projection h = x @ Wup + LIF -> spike bits in gmask.
// EF-QUARTER split (fq), wave covers 32 f (2 tiles), 2048 working blocks.
// gid = (e*4+fq)*128 + tile: tile in low 3 bits -> XCD = tile%8, so every
// XCD gets ~1/8 of EVERY expert's tiles (work-balanced under skew).
// ---------------------------------------------------------------------------
__global__ __launch_bounds__(256, 4) void moe_up(
    const float* __restrict__ x, const float* __restrict__ wup,
    const int* __restrict__ cnt, const int* __restrict__ ltok,
    unsigned short* __restrict__ gmask)
{
    const int gid   = blockIdx.x;
    const int tile  = gid & 127;
    const int chunk = gid >> 7;
    const int fq    = chunk & 3;
    const int e     = chunk >> 2;
    const int c     = cnt[e];
    const int base  = tile * TP;
    if (base >= c) return;

    const int tid = threadIdx.x;
    const int w   = tid >> 6;     // wave 0..3
    const int l   = tid & 63;

    __shared__ int    s_tok[TP];
    __shared__ float  xs[32][132];        // staged x rows (row = pair*4+t), 16.9 KB
    __shared__ double dtile[4][16][17];   // per-wave D round-trip, 8.7 KB
    __shared__ int s_bad;

    if (tid < TP) {
        const int idx = base + tid;
        s_tok[tid] = (idx < c) ? ltok[e * NTOK + idx] : ltok[e * NTOK + base];
    }
    if (tid == 0) s_bad = 0;
    __syncthreads();

    const Frag fr = probe_layout(l);
    if (fr.bad) atomicOr(&s_bad, 1);
    __syncthreads();

    if (s_bad) {
        // scalar fallback (dead in practice) — this block's EF-quarter only
        unsigned short* gm16 = gmask;
        for (int i = tid; i < TP * 4 * 8; i += 256) {   // zero our 8 ushorts/row
            const int pr = i >> 5;
            gm16[gm_row(e, base + pr, (i >> 3) & 3) + fq * 8 + (i & 7)] = 0;
        }
        __syncthreads();
        for (int ci = tid; ci < TP * 128; ci += 256) {
            const int pair = ci >> 7;
            const int f    = fq * 128 + (ci & 127);
            const float* wc = wup + (size_t)e * D_ * EF + f;
            const float* xb = x + (size_t)s_tok[pair] * D_;
            double hh[4] = {0.0, 0.0, 0.0, 0.0};
            for (int d = 0; d < D_; ++d) {
                const double wv = (double)wc[(size_t)d * EF];
#pragma unroll
                for (int t = 0; t < 4; ++t)
                    hh[t] = fma((double)xb[(size_t)t * NTOK * D_ + d], wv, hh[t]);
            }
            double v = 0.0;
#pragma unroll
            for (int t = 0; t < 4; ++t) {
                v = 0.9 * v + hh[t];
                if (v - 1.0 >= 0.0) {
                    v -= 1.0;
                    atomicOr((unsigned*)&gm16[gm_row(e, base + pair, t) + ((f >> 4) & ~1)],
                             1u << (f & 31));
                }
            }
        }
        return;
    }

    // -------- MFMA path --------
    const float* bp = wup + (size_t)e * D_ * EF + (size_t)fr.kB * EF
                    + fq * 128 + w * 32 + fr.uB;

    const d4 zz = {0.0, 0.0, 0.0, 0.0};
    d4 acc0[2], acc1[2];
#pragma unroll
    for (int j = 0; j < 2; ++j) { acc0[j] = zz; acc1[j] = zz; }

    const int arow0 = fr.vA;        // xs row for row-group 0 (pairs 0..3)
    const int arow1 = 16 + fr.vA;   // row-group 1 (pairs 4..7)

    for (int kc = 0; kc < 8; ++kc) {
        __syncthreads();   // previous chunk's readers done
#pragma unroll
        for (int v = 0; v < 4; ++v) {
            const int idx = v * 256 + tid;        // 0..1023 float4 slots
            const int row = idx >> 5;             // 0..31 = pair*4+t
            const int c4  = (idx & 31) << 2;      // 0,4,..,124
            const int pr  = row >> 2, t = row & 3;
            *(float4*)&xs[row][c4] =
                *(const float4*)&x[((size_t)t * NTOK + s_tok[pr]) * D_ + kc * 128 + c4];
        }
        __syncthreads();

#pragma unroll 4
        for (int kk2 = 0; kk2 < 32; ++kk2) {
            const double aD0 = (double)xs[arow0][kk2 * 4 + fr.kA];
            const double aD1 = (double)xs[arow1][kk2 * 4 + fr.kA];
            float b[2];
            b[0] = bp[0];
            b[1] = bp[16];
#pragma unroll
            for (int j = 0; j < 2; ++j) {
                const double bD = (double)b[j];
                acc0[j] = __builtin_amdgcn_mfma_f64_16x16x4f64(aD0, bD, acc0[j], 0, 0, 0);
                acc1[j] = __builtin_amdgcn_mfma_f64_16x16x4f64(aD1, bD, acc1[j], 0, 0, 0);
            }
            bp += (size_t)4 * EF;
        }
    }

    // epilogue: per group, per tile: LDS round-trip -> canonical LIF -> gmask
    const int pp = l >> 4;
    const int cc = l & 15;
#pragma unroll
    for (int g = 0; g < 2; ++g) {
#pragma unroll
        for (int j = 0; j < 2; ++j) {
            const d4 av = g ? acc1[j] : acc0[j];
#pragma unroll
            for (int r = 0; r < 4; ++r) dtile[w][fr.vC[r]][fr.uC[r]] = av[r];
            double v = 0.0;
#pragma unroll
            for (int t = 0; t < 4; ++t) {
                v = 0.9 * v + dtile[w][pp * 4 + t][cc];
                const bool s = (v - 1.0 >= 0.0);
                if (s) v -= 1.0;
                const unsigned long long bal = __ballot(s);
                if (l < 4)
                    gmask[gm_row(e, base + g * 4 + l, t) + (fq * 8 + w * 2 + j)] =
                        (unsigned short)(bal >> (l * 16));
            }
        }
    }
}

// ---------------------------------------------------------------------------
// Kernel 3b: down projection — R12 shape (D-quarter, 4:8) with the balanced
// gid layout: gid = (e*4+dq)*128 + tile, XCD = tile%8.
// ---------------------------------------------------------------------------
__global__ __launch_bounds__(256, 4) void moe_down(
    const float* __restrict__ wdn,
    const int* __restrict__ cnt, const int* __restrict__ ltok,
    const double* __restrict__ lw, const unsigned short* __restrict__ gmask,
    float* __restrict__ out)
{
    const int gid   = blockIdx.x;
    const int tile  = gid & 127;
    const int chunk = gid >> 7;
    const int dq    = chunk & 3;
    const int e     = chunk >> 2;
    const int c     = cnt[e];
    const int base  = tile * TP;
    if (base >= c) return;

    const int tid = threadIdx.x;
    const int w   = tid >> 6;
    const int l   = tid & 63;

    __shared__ int    s_tok[TP];
    __shared__ double s_w[TP];
    __shared__ unsigned hm[32][17];       // [pair*4+t][word] spike bits (padded)
    __shared__ double dtile[4][16][17];
    __shared__ int s_bad;

    if (tid < TP) {
        const int idx = base + tid;
        if (idx < c) { s_tok[tid] = ltok[e * NTOK + idx]; s_w[tid] = lw[e * NTOK + idx]; }
        else         { s_tok[tid] = ltok[e * NTOK + base]; s_w[tid] = 0.0; }
    }
    if (tid == 0) s_bad = 0;
    const unsigned* gm32 = (const unsigned*)gmask;
#pragma unroll
    for (int i = tid; i < 32 * 16; i += 256) {
        const int r = i >> 4, wd = i & 15;
        hm[r][wd] = gm32[(gm_row(e, base + (r >> 2), r & 3) >> 1) + wd];
    }
    __syncthreads();

    const Frag fr = probe_layout(l);
    if (fr.bad) atomicOr(&s_bad, 1);
    __syncthreads();

    if (s_bad) {
        // scalar fallback (dead in practice) — this block's d-quarter only
        for (int ci = tid; ci < TP * 256; ci += 256) {
            const int pair = ci >> 8;
            const int d    = dq * 256 + (ci & 255);
            const double wgt2 = s_w[pair];
            const int    nn2  = s_tok[pair];
            const float* wc = wdn + (size_t)e * EF * D_ + d;
            double o[4] = {0.0, 0.0, 0.0, 0.0};
            for (int f = 0; f < EF; ++f) {
                const double wv = (double)wc[(size_t)f * D_];
#pragma unroll
                for (int t = 0; t < 4; ++t)
                    if ((hm[pair * 4 + t][f >> 5] >> (f & 31)) & 1) o[t] += wv;
            }
            double v = 0.0;
#pragma unroll
            for (int t = 0; t < 4; ++t) {
                v = 0.9 * v + o[t];
                if (v - 1.0 >= 0.0) {
                    v -= 1.0;
                    if (wgt2 != 0.0)
                        atomicAdd(&out[((size_t)t * NTOK + nn2) * D_ + d], (float)wgt2);
                }
            }
        }
        return;
    }

    // -------- MFMA path (single d-quarter) --------
    const d4 zz = {0.0, 0.0, 0.0, 0.0};
    const int pp = l >> 4;
    const int cc = l & 15;

    const float* dp = wdn + (size_t)e * EF * D_ + (size_t)fr.kB * D_
                    + dq * 256 + w * 64 + fr.uB;

    d4 acc0[4], acc1[4];
#pragma unroll
    for (int j = 0; j < 4; ++j) { acc0[j] = zz; acc1[j] = zz; }

    float bC[4];
#pragma unroll
    for (int j = 0; j < 4; ++j) bC[j] = dp[j * 16];
    unsigned m0 = hm[fr.vA][0];
    unsigned m1 = hm[16 + fr.vA][0];

#pragma unroll 1
    for (int wd = 0; wd < 16; ++wd) {
        const unsigned cm0 = m0, cm1 = m1;
        const int nw = (wd < 15) ? (wd + 1) : wd;
        m0 = hm[fr.vA][nw];              // prefetch next word's masks
        m1 = hm[16 + fr.vA][nw];
#pragma unroll
        for (int k2 = 0; k2 < 8; ++k2) {
            const bool last = (wd == 15) && (k2 == 7);
            const float* dn_ = last ? dp : (dp + (size_t)4 * D_);
            float bN[4];
#pragma unroll
            for (int j = 0; j < 4; ++j) bN[j] = dn_[j * 16];   // prefetch next kk

            const int bit = k2 * 4 + fr.kA;
            const double aD0 = ((cm0 >> bit) & 1u) ? 1.0 : 0.0;
            const double aD1 = ((cm1 >> bit) & 1u) ? 1.0 : 0.0;
#pragma unroll
            for (int j = 0; j < 4; ++j) {
                const double bD = (double)bC[j];
                acc0[j] = __builtin_amdgcn_mfma_f64_16x16x4f64(aD0, bD, acc0[j], 0, 0, 0);
                acc1[j] = __builtin_amdgcn_mfma_f64_16x16x4f64(aD1, bD, acc1[j], 0, 0, 0);
            }
#pragma unroll
            for (int j = 0; j < 4; ++j) bC[j] = bN[j];
            dp = dn_;
        }
    }

    // epilogue: round-trip -> canonical LIF -> weighted spike scatter
#pragma unroll
    for (int g = 0; g < 2; ++g) {
        const int pair = g * 4 + pp;
        const double wgt = s_w[pair];
        const int    nn  = s_tok[pair];
#pragma unroll
        for (int j = 0; j < 4; ++j) {
            const d4 av = g ? acc1[j] : acc0[j];
#pragma unroll
            for (int r = 0; r < 4; ++r) dtile[w][fr.vC[r]][fr.uC[r]] = av[r];
            const int d = dq * 256 + w * 64 + j * 16 + cc;
            double v = 0.0;
#pragma unroll
            for (int t = 0; t < 4; ++t) {
                v = 0.9 * v + dtile[w][pp * 4 + t][cc];
                if (v - 1.0 >= 0.0) {
                    v -= 1.0;
                    if (wgt != 0.0)
                        atomicAdd(&out[((size_t)t * NTOK + nn) * D_ + d], (float)wgt);
                }
            }
        }
    }
}

// ---------------------------------------------------------------------------
extern "C" void kernel_launch(void* const* d_in, const int* in_sizes, int n_in,
                              void* d_out, int out_size, void* d_ws, size_t ws_size,
                              hipStream_t stream)
{
    const float* x    = (const float*)d_in[0];
    const float* wup  = (const float*)d_in[1];
    const float* wdn  = (const float*)d_in[2];
    const float* bias = (const float*)d_in[3];
    float* out = (float*)d_out;
    char*  ws  = (char*)d_ws;

    double* rp   = (double*)(ws + WS_RP);
    int*    cnt  = (int*)(ws + WS_CNT);
    int*    ltok = (int*)(ws + WS_LTOK);
    double* lw   = (double*)(ws + WS_LW);
    unsigned short* gmask = (unsigned short*)(ws + WS_GMASK);

    hipMemsetAsync(d_out, 0, (size_t)out_size * sizeof(float), stream);
    hipMemsetAsync(cnt, 0, NE * sizeof(int), stream);

    moe_routing<<<NTOK, 256, 0, stream>>>(x, bias, rp, cnt, ltok, lw);
    moe_finalize<<<1, 256, 0, stream>>>(rp, cnt, out + (size_t)T_ * NTOK * D_);
    moe_up<<<NE * 4 * 128, 256, 0, stream>>>(x, wup, cnt, ltok, gmask);
    moe_down<<<NE * 4 * 128, 256, 0, stream>>>(wdn, cnt, ltok, lw, gmask, out);
}

// Round 14
// 715.327 us; speedup vs baseline: 1.0458x; 1.0458x over previous
//
#include <hip/hip_runtime.h>
#include <cstdint>
#include <cstddef>

#define T_   4
#define NTOK 2048
#define D_   1024
#define EF   512
#define NE   8
#define TP   8   // (token,expert) pairs per tile -> 32 rows = 2 MFMA row-groups

typedef __attribute__((ext_vector_type(4))) double d4;

// ---------------- ws layout ----------------
#define WS_RP    0        // double[NTOK*NE]                     131072 B
#define WS_CNT   131072   // int[NE]                             32 B
#define WS_LTOK  131104   // int[NE*NTOK]                        65536 B
#define WS_LW    196640   // double[NE*NTOK]                     131072 B
#define WS_GMASK 327712   // ushort[NE*2048*4][32]  spike bits   4 MiB

// ---------------------------------------------------------------------------
// Kernel 1: routing (unchanged — verified exact, absmax 0.0)
// ---------------------------------------------------------------------------
__global__ __launch_bounds__(256) void moe_routing(
    const float* __restrict__ x, const float* __restrict__ bias,
    double* __restrict__ rp, int* __restrict__ cnt,
    int* __restrict__ ltok, double* __restrict__ lw)
{
    const int n   = blockIdx.x;
    const int tid = threadIdx.x;
    __shared__ int scnt[NE];
    if (tid < NE) scnt[tid] = 0;
    __syncthreads();

    int c = 0;
#pragma unroll
    for (int j = 0; j < 4; ++j) {
        const int d = j * 256 + tid;
        double v = 0.0;
#pragma unroll
        for (int t = 0; t < T_; ++t) {
            v = 0.9 * v + (double)x[((size_t)t * NTOK + n) * D_ + d];
            if (v - 1.0 >= 0.0) { ++c; v -= 1.0; }
        }
    }
    c += __shfl_xor(c, 1);
    c += __shfl_xor(c, 2);
    c += __shfl_xor(c, 4);
    if ((tid & 7) == 0) atomicAdd(&scnt[(tid >> 3) & 7], c);
    __syncthreads();

    if (tid == 0) {
        double es[NE];
#pragma unroll
        for (int e = 0; e < NE; ++e)
            es[e] = (double)scnt[e] * (1.0 / 512.0) + (double)bias[e];

        int i0 = 0; double b0 = es[0];
        for (int e = 1; e < NE; ++e) if (es[e] > b0) { b0 = es[e]; i0 = e; }
        int i1 = -1; double b1 = -1e300;
        for (int e = 0; e < NE; ++e) if (e != i0 && es[e] > b1) { b1 = es[e]; i1 = e; }

        const double e1 = exp(b1 - b0);
        const double w0 = 1.0 / (1.0 + e1);
        const double w1 = e1 / (1.0 + e1);

        double mx = es[0];
        for (int e = 1; e < NE; ++e) mx = es[e] > mx ? es[e] : mx;
        double s = 0.0, ex[NE];
        for (int e = 0; e < NE; ++e) { ex[e] = exp(es[e] - mx); s += ex[e]; }
        for (int e = 0; e < NE; ++e) rp[(size_t)n * NE + e] = ex[e] / s;

        int s0 = atomicAdd(&cnt[i0], 1);
        ltok[i0 * NTOK + s0] = n; lw[i0 * NTOK + s0] = w0;
        int s1 = atomicAdd(&cnt[i1], 1);
        ltok[i1 * NTOK + s1] = n; lw[i1 * NTOK + s1] = w1;
    }
}

// ---------------------------------------------------------------------------
// Kernel 2: load-balance loss (unchanged)
// ---------------------------------------------------------------------------
__global__ __launch_bounds__(256) void moe_finalize(
    const double* __restrict__ rp, const int* __restrict__ cnt,
    float* __restrict__ out_lb)
{
    __shared__ double red[256][NE];
    const int tid = threadIdx.x;
    double a[NE];
#pragma unroll
    for (int e = 0; e < NE; ++e) a[e] = 0.0;
    for (int n = tid; n < NTOK; n += 256)
#pragma unroll
        for (int e = 0; e < NE; ++e) a[e] += rp[(size_t)n * NE + e];
#pragma unroll
    for (int e = 0; e < NE; ++e) red[tid][e] = a[e];
    __syncthreads();
    if (tid < NE) {
        double s = 0.0;
        for (int i = 0; i < 256; ++i) s += red[i][tid];
        red[0][tid] = s;
    }
    __syncthreads();
    if (tid == 0) {
        double lb = 0.0;
#pragma unroll
        for (int e = 0; e < NE; ++e)
            lb += ((double)cnt[e] / (double)(NTOK * 2)) * (red[0][e] / (double)NTOK);
        out_lb[0] = (float)(8.0 * lb);
    }
}

// probe decode (verified on HW in R5): fam0 lane=16k+idx -> val=96+4idx;
// fam1 lane=4idx+k -> val=6+16idx.
__device__ __forceinline__ int dec_idx(double val, int* fam) {
    const double r0 = (val - 96.0) * 0.25;
    const int i0 = (int)r0;
    if ((double)i0 == r0 && i0 >= 0 && i0 < 16) { *fam = 0; return i0; }
    const double r1 = (val - 6.0) * 0.0625;
    const int i1 = (int)r1;
    if ((double)i1 == r1 && i1 >= 0 && i1 < 16) { *fam = 1; return i1; }
    *fam = -1; return 0;
}

struct Frag {
    int vA, kA, uB, kB;   // A-row / A-k / B-col / B-k index of this lane
    int vC[4], uC[4];     // D (row,col) of acc reg r
    int bad;
};

__device__ __forceinline__ Frag probe_layout(int l) {
    Frag fr; fr.bad = 0;
    const d4 zz = {0.0, 0.0, 0.0, 0.0};
    const double dl = (double)l;
    const d4 Dv = __builtin_amdgcn_mfma_f64_16x16x4f64(dl, 1.0, zz, 0, 0, 0);
    const d4 Du = __builtin_amdgcn_mfma_f64_16x16x4f64(1.0, dl, zz, 0, 0, 0);
    int famA = -1, famB = -1;
#pragma unroll
    for (int r = 0; r < 4; ++r) {
        int fa, fb;
        fr.vC[r] = dec_idx(Dv[r], &fa);
        fr.uC[r] = dec_idx(Du[r], &fb);
        if (r == 0) { famA = fa; famB = fb; }
        fr.bad |= (fa != famA) | (fb != famB) | (fa < 0) | (fb < 0);
    }
    fr.vA = (famA == 0) ? (l & 15) : (l >> 2);
    fr.kA = (famA == 0) ? (l >> 4) : (l & 3);
    fr.uB = (famB == 0) ? (l & 15) : (l >> 2);
    fr.kB = (famB == 0) ? (l >> 4) : (l & 3);
    const d4 D3 = __builtin_amdgcn_mfma_f64_16x16x4f64(
        (double)(1 << fr.kA), (double)(16 << fr.kB), zz, 0, 0, 0);
#pragma unroll
    for (int r = 0; r < 4; ++r) fr.bad |= (D3[r] != 1360.0);
    return fr;
}

// gmask row of 32 ushorts per (e, pairIdx, t)
__device__ __forceinline__ size_t gm_row(int e, int pairIdx, int t) {
    return ((size_t)((e << 11) + pairIdx) * 4 + t) * 32;
}

// ---------------------------------------------------------------------------
// Kernel 3a: up projection h = x @ Wup + LIF -> spike bits in gmask.
// R12 config (EF-half split, e=gid&7 -> expert pinned to XCD for weight-L2
// locality) + T14 async-stage split: next kc chunk loads into regs BEFORE
// the current chunk's MFMA loop; LDS write happens after, between barriers.
// ---------------------------------------------------------------------------
__global__ __launch_bounds__(256, 4) void moe_up(
    const float* __restrict__ x, const float* __restrict__ wup,
    const int* __restrict__ cnt, const int* __restrict__ ltok,
    unsigned short* __restrict__ gmask)
{
    const int gid  = blockIdx.x;
    const int e    = gid & 7;
    const int hf   = (gid >> 3) & 1;
    const int tile = gid >> 4;
    const int c    = cnt[e];
    const int base = tile * TP;
    if (base >= c) return;

    const int tid = threadIdx.x;
    const int w   = tid >> 6;     // wave 0..3
    const int l   = tid & 63;

    __shared__ int    s_tok[TP];
    __shared__ float  xs[32][132];        // staged x rows (row = pair*4+t), 16.9 KB
    __shared__ double dtile[4][16][17];   // per-wave D round-trip, 8.7 KB
    __shared__ int s_bad;

    if (tid < TP) {
        const int idx = base + tid;
        s_tok[tid] = (idx < c) ? ltok[e * NTOK + idx] : ltok[e * NTOK + base];
    }
    if (tid == 0) s_bad = 0;
    __syncthreads();

    const Frag fr = probe_layout(l);
    if (fr.bad) atomicOr(&s_bad, 1);
    __syncthreads();

    if (s_bad) {
        // scalar fallback (dead in practice) — this block's EF-half only
        unsigned short* gm16 = gmask;
        for (int i = tid; i < TP * 4 * 16; i += 256) {   // zero our 16 ushorts/row
            const int pr = i >> 6;
            gm16[gm_row(e, base + pr, (i >> 4) & 3) + hf * 16 + (i & 15)] = 0;
        }
        __syncthreads();
        for (int ci = tid; ci < TP * 256; ci += 256) {
            const int pair = ci >> 8;
            const int f    = hf * 256 + (ci & 255);
            const float* wc = wup + (size_t)e * D_ * EF + f;
            const float* xb = x + (size_t)s_tok[pair] * D_;
            double hh[4] = {0.0, 0.0, 0.0, 0.0};
            for (int d = 0; d < D_; ++d) {
                const double wv = (double)wc[(size_t)d * EF];
#pragma unroll
                for (int t = 0; t < 4; ++t)
                    hh[t] = fma((double)xb[(size_t)t * NTOK * D_ + d], wv, hh[t]);
            }
            double v = 0.0;
#pragma unroll
            for (int t = 0; t < 4; ++t) {
                v = 0.9 * v + hh[t];
                if (v - 1.0 >= 0.0) {
                    v -= 1.0;
                    atomicOr((unsigned*)&gm16[gm_row(e, base + pair, t) + ((f >> 4) & ~1)],
                             1u << (f & 31));
                }
            }
        }
        return;
    }

    // -------- MFMA path --------
    const float* bp = wup + (size_t)e * D_ * EF + (size_t)fr.kB * EF
                    + hf * 256 + w * 64 + fr.uB;

    const d4 zz = {0.0, 0.0, 0.0, 0.0};
    d4 acc0[4], acc1[4];
#pragma unroll
    for (int j = 0; j < 4; ++j) { acc0[j] = zz; acc1[j] = zz; }

    const int arow0 = fr.vA;        // xs row for row-group 0 (pairs 0..3)
    const int arow1 = 16 + fr.vA;   // row-group 1 (pairs 4..7)

    // staging-address components (each thread owns 4 float4 slots)
    int st_row[4], st_c4[4];
    const float* st_src[4];
#pragma unroll
    for (int v = 0; v < 4; ++v) {
        const int idx = v * 256 + tid;        // 0..1023 float4 slots
        st_row[v] = idx >> 5;                 // 0..31 = pair*4+t
        st_c4[v]  = (idx & 31) << 2;          // 0,4,..,124
        const int pr = st_row[v] >> 2, t = st_row[v] & 3;
        st_src[v] = &x[((size_t)t * NTOK + s_tok[pr]) * D_ + st_c4[v]];
    }

    // prologue: load chunk 0 into regs
    float4 rx[4];
#pragma unroll
    for (int v = 0; v < 4; ++v) rx[v] = *(const float4*)st_src[v];

#pragma unroll 1
    for (int kc = 0; kc < 8; ++kc) {
        __syncthreads();   // previous chunk's readers done
#pragma unroll
        for (int v = 0; v < 4; ++v)
            *(float4*)&xs[st_row[v]][st_c4[v]] = rx[v];
        __syncthreads();

        // T14: issue next chunk's loads BEFORE the MFMA loop — latency hides
        if (kc < 7) {
#pragma unroll
            for (int v = 0; v < 4; ++v)
                rx[v] = *(const float4*)(st_src[v] + (kc + 1) * 128);
        }

#pragma unroll 4
        for (int kk2 = 0; kk2 < 32; ++kk2) {
            const double aD0 = (double)xs[arow0][kk2 * 4 + fr.kA];
            const double aD1 = (double)xs[arow1][kk2 * 4 + fr.kA];
            float b[4];
#pragma unroll
            for (int j = 0; j < 4; ++j) b[j] = bp[j * 16];
#pragma unroll
            for (int j = 0; j < 4; ++j) {
                const double bD = (double)b[j];
                acc0[j] = __builtin_amdgcn_mfma_f64_16x16x4f64(aD0, bD, acc0[j], 0, 0, 0);
                acc1[j] = __builtin_amdgcn_mfma_f64_16x16x4f64(aD1, bD, acc1[j], 0, 0, 0);
            }
            bp += (size_t)4 * EF;
        }
    }

    // epilogue: per group, per tile: LDS round-trip -> canonical LIF -> gmask
    const int pp = l >> 4;
    const int cc = l & 15;
#pragma unroll
    for (int g = 0; g < 2; ++g) {
#pragma unroll
        for (int j = 0; j < 4; ++j) {
            const d4 av = g ? acc1[j] : acc0[j];
#pragma unroll
            for (int r = 0; r < 4; ++r) dtile[w][fr.vC[r]][fr.uC[r]] = av[r];
            double v = 0.0;
#pragma unroll
            for (int t = 0; t < 4; ++t) {
                v = 0.9 * v + dtile[w][pp * 4 + t][cc];
                const bool s = (v - 1.0 >= 0.0);
                if (s) v -= 1.0;
                const unsigned long long bal = __ballot(s);
                if (l < 4)
                    gmask[gm_row(e, base + g * 4 + l, t) + (hf * 16 + w * 4 + j)] =
                        (unsigned short)(bal >> (l * 16));
            }
        }
    }
}

// ---------------------------------------------------------------------------
// Kernel 3b: down projection — exact R12 config (D-quarter split, e=gid&7
// XCD-pinned, 4 loads : 8 MFMA per kk, acc 32 VGPR, 2048 working blocks).
// ---------------------------------------------------------------------------
__global__ __launch_bounds__(256, 4) void moe_down(
    const float* __restrict__ wdn,
    const int* __restrict__ cnt, const int* __restrict__ ltok,
    const double* __restrict__ lw, const unsigned short* __restrict__ gmask,
    float* __restrict__ out)
{
    const int gid  = blockIdx.x;
    const int e    = gid & 7;
    const int dq   = (gid >> 3) & 3;
    const int tile = gid >> 5;
    const int c    = cnt[e];
    const int base = tile * TP;
    if (base >= c) return;

    const int tid = threadIdx.x;
    const int w   = tid >> 6;
    const int l   = tid & 63;

    __shared__ int    s_tok[TP];
    __shared__ double s_w[TP];
    __shared__ unsigned hm[32][17];       // [pair*4+t][word] spike bits (padded)
    __shared__ double dtile[4][16][17];
    __shared__ int s_bad;

    if (tid < TP) {
        const int idx = base + tid;
        if (idx < c) { s_tok[tid] = ltok[e * NTOK + idx]; s_w[tid] = lw[e * NTOK + idx]; }
        else         { s_tok[tid] = ltok[e * NTOK + base]; s_w[tid] = 0.0; }
    }
    if (tid == 0) s_bad = 0;
    const unsigned* gm32 = (const unsigned*)gmask;
#pragma unroll
    for (int i = tid; i < 32 * 16; i += 256) {
        const int r = i >> 4, wd = i & 15;
        hm[r][wd] = gm32[(gm_row(e, base + (r >> 2), r & 3) >> 1) + wd];
    }
    __syncthreads();

    const Frag fr = probe_layout(l);
    if (fr.bad) atomicOr(&s_bad, 1);
    __syncthreads();

    if (s_bad) {
        // scalar fallback (dead in practice) — this block's d-quarter only
        for (int ci = tid; ci < TP * 256; ci += 256) {
            const int pair = ci >> 8;
            const int d    = dq * 256 + (ci & 255);
            const double wgt2 = s_w[pair];
            const int    nn2  = s_tok[pair];
            const float* wc = wdn + (size_t)e * EF * D_ + d;
            double o[4] = {0.0, 0.0, 0.0, 0.0};
            for (int f = 0; f < EF; ++f) {
                const double wv = (double)wc[(size_t)f * D_];
#pragma unroll
                for (int t = 0; t < 4; ++t)
                    if ((hm[pair * 4 + t][f >> 5] >> (f & 31)) & 1) o[t] += wv;
            }
            double v = 0.0;
#pragma unroll
            for (int t = 0; t < 4; ++t) {
                v = 0.9 * v + o[t];
                if (v - 1.0 >= 0.0) {
                    v -= 1.0;
                    if (wgt2 != 0.0)
                        atomicAdd(&out[((size_t)t * NTOK + nn2) * D_ + d], (float)wgt2);
                }
            }
        }
        return;
    }

    // -------- MFMA path (single d-quarter) --------
    const d4 zz = {0.0, 0.0, 0.0, 0.0};
    const int pp = l >> 4;
    const int cc = l & 15;

    const float* dp = wdn + (size_t)e * EF * D_ + (size_t)fr.kB * D_
                    + dq * 256 + w * 64 + fr.uB;

    d4 acc0[4], acc1[4];
#pragma unroll
    for (int j = 0; j < 4; ++j) { acc0[j] = zz; acc1[j] = zz; }

    float bC[4];
#pragma unroll
    for (int j = 0; j < 4; ++j) bC[j] = dp[j * 16];
    unsigned m0 = hm[fr.vA][0];
    unsigned m1 = hm[16 + fr.vA][0];

#pragma unroll 1
    for (int wd = 0; wd < 16; ++wd) {
        const unsigned cm0 = m0, cm1 = m1;
        const int nw = (wd < 15) ? (wd + 1) : wd;
        m0 = hm[fr.vA][nw];              // prefetch next word's masks
        m1 = hm[16 + fr.vA][nw];
#pragma unroll
        for (int k2 = 0; k2 < 8; ++k2) {
            const bool last = (wd == 15) && (k2 == 7);
            const float* dn_ = last ? dp : (dp + (size_t)4 * D_);
            float bN[4];
#pragma unroll
            for (int j = 0; j < 4; ++j) bN[j] = dn_[j * 16];   // prefetch next kk

            const int bit = k2 * 4 + fr.kA;
            const double aD0 = ((cm0 >> bit) & 1u) ? 1.0 : 0.0;
            const double aD1 = ((cm1 >> bit) & 1u) ? 1.0 : 0.0;
#pragma unroll
            for (int j = 0; j < 4; ++j) {
                const double bD = (double)bC[j];
                acc0[j] = __builtin_amdgcn_mfma_f64_16x16x4f64(aD0, bD, acc0[j], 0, 0, 0);
                acc1[j] = __builtin_amdgcn_mfma_f64_16x16x4f64(aD1, bD, acc1[j], 0, 0, 0);
            }
#pragma unroll
            for (int j = 0; j < 4; ++j) bC[j] = bN[j];
            dp = dn_;
        }
    }

    // epilogue: round-trip -> canonical LIF -> weighted spike scatter
#pragma unroll
    for (int g = 0; g < 2; ++g) {
        const int pair = g * 4 + pp;
        const double wgt = s_w[pair];
        const int    nn  = s_tok[pair];
#pragma unroll
        for (int j = 0; j < 4; ++j) {
            const d4 av = g ? acc1[j] : acc0[j];
#pragma unroll
            for (int r = 0; r < 4; ++r) dtile[w][fr.vC[r]][fr.uC[r]] = av[r];
            const int d = dq * 256 + w * 64 + j * 16 + cc;
            double v = 0.0;
#pragma unroll
            for (int t = 0; t < 4; ++t) {
                v = 0.9 * v + dtile[w][pp * 4 + t][cc];
                if (v - 1.0 >= 0.0) {
                    v -= 1.0;
                    if (wgt != 0.0)
                        atomicAdd(&out[((size_t)t * NTOK + nn) * D_ + d], (float)wgt);
                }
            }
        }
    }
}

// ---------------------------------------------------------------------------
extern "C" void kernel_launch(void* const* d_in, const int* in_sizes, int n_in,
                              void* d_out, int out_size, void* d_ws, size_t ws_size,
                              hipStream_t stream)
{
    const float* x    = (const float*)d_in[0];
    const float* wup  = (const float*)d_in[1];
    const float* wdn  = (const float*)d_in[2];
    const float* bias = (const float*)d_in[3];
    float* out = (float*)d_out;
    char*  ws  = (char*)d_ws;

    double* rp   = (double*)(ws + WS_RP);
    int*    cnt  = (int*)(ws + WS_CNT);
    int*    ltok = (int*)(ws + WS_LTOK);
    double* lw   = (double*)(ws + WS_LW);
    unsigned short* gmask = (unsigned short*)(ws + WS_GMASK);

    hipMemsetAsync(d_out, 0, (size_t)out_size * sizeof(float), stream);
    hipMemsetAsync(cnt, 0, NE * sizeof(int), stream);

    moe_routing<<<NTOK, 256, 0, stream>>>(x, bias, rp, cnt, ltok, lw);
    moe_finalize<<<1, 256, 0, stream>>>(rp, cnt, out + (size_t)T_ * NTOK * D_);
    moe_up<<<NE * 1024, 256, 0, stream>>>(x, wup, cnt, ltok, gmask);
    moe_down<<<NE * 1024, 256, 0, stream>>>(wdn, cnt, ltok, lw, gmask, out);
}

// Round 15
// 699.846 us; speedup vs baseline: 1.0690x; 1.0221x over previous
//
#include <hip/hip_runtime.h>
#include <cstdint>
#include <cstddef>

#define T_   4
#define NTOK 2048
#define D_   1024
#define EF   512
#define NE   8
#define TP   8   // (token,expert) pairs per tile -> 32 rows = 2 MFMA row-groups

typedef __attribute__((ext_vector_type(4))) double d4;

// ---------------- ws layout ----------------
#define WS_RP    0        // double[NTOK*NE]                     131072 B
#define WS_CNT   131072   // int[NE]                             32 B
#define WS_LTOK  131104   // int[NE*NTOK]                        65536 B
#define WS_LW    196640   // double[NE*NTOK]                     131072 B
#define WS_GMASK 327712   // ushort[NE*2048*4][32]  spike bits   4 MiB

// ---------------------------------------------------------------------------
// Kernel 1: routing (unchanged — verified exact, absmax 0.0)
// ---------------------------------------------------------------------------
__global__ __launch_bounds__(256) void moe_routing(
    const float* __restrict__ x, const float* __restrict__ bias,
    double* __restrict__ rp, int* __restrict__ cnt,
    int* __restrict__ ltok, double* __restrict__ lw)
{
    const int n   = blockIdx.x;
    const int tid = threadIdx.x;
    __shared__ int scnt[NE];
    if (tid < NE) scnt[tid] = 0;
    __syncthreads();

    int c = 0;
#pragma unroll
    for (int j = 0; j < 4; ++j) {
        const int d = j * 256 + tid;
        double v = 0.0;
#pragma unroll
        for (int t = 0; t < T_; ++t) {
            v = 0.9 * v + (double)x[((size_t)t * NTOK + n) * D_ + d];
            if (v - 1.0 >= 0.0) { ++c; v -= 1.0; }
        }
    }
    c += __shfl_xor(c, 1);
    c += __shfl_xor(c, 2);
    c += __shfl_xor(c, 4);
    if ((tid & 7) == 0) atomicAdd(&scnt[(tid >> 3) & 7], c);
    __syncthreads();

    if (tid == 0) {
        double es[NE];
#pragma unroll
        for (int e = 0; e < NE; ++e)
            es[e] = (double)scnt[e] * (1.0 / 512.0) + (double)bias[e];

        int i0 = 0; double b0 = es[0];
        for (int e = 1; e < NE; ++e) if (es[e] > b0) { b0 = es[e]; i0 = e; }
        int i1 = -1; double b1 = -1e300;
        for (int e = 0; e < NE; ++e) if (e != i0 && es[e] > b1) { b1 = es[e]; i1 = e; }

        const double e1 = exp(b1 - b0);
        const double w0 = 1.0 / (1.0 + e1);
        const double w1 = e1 / (1.0 + e1);

        double mx = es[0];
        for (int e = 1; e < NE; ++e) mx = es[e] > mx ? es[e] : mx;
        double s = 0.0, ex[NE];
        for (int e = 0; e < NE; ++e) { ex[e] = exp(es[e] - mx); s += ex[e]; }
        for (int e = 0; e < NE; ++e) rp[(size_t)n * NE + e] = ex[e] / s;

        int s0 = atomicAdd(&cnt[i0], 1);
        ltok[i0 * NTOK + s0] = n; lw[i0 * NTOK + s0] = w0;
        int s1 = atomicAdd(&cnt[i1], 1);
        ltok[i1 * NTOK + s1] = n; lw[i1 * NTOK + s1] = w1;
    }
}

// ---------------------------------------------------------------------------
// Kernel 2: load-balance loss (unchanged)
// ---------------------------------------------------------------------------
__global__ __launch_bounds__(256) void moe_finalize(
    const double* __restrict__ rp, const int* __restrict__ cnt,
    float* __restrict__ out_lb)
{
    __shared__ double red[256][NE];
    const int tid = threadIdx.x;
    double a[NE];
#pragma unroll
    for (int e = 0; e < NE; ++e) a[e] = 0.0;
    for (int n = tid; n < NTOK; n += 256)
#pragma unroll
        for (int e = 0; e < NE; ++e) a[e] += rp[(size_t)n * NE + e];
#pragma unroll
    for (int e = 0; e < NE; ++e) red[tid][e] = a[e];
    __syncthreads();
    if (tid < NE) {
        double s = 0.0;
        for (int i = 0; i < 256; ++i) s += red[i][tid];
        red[0][tid] = s;
    }
    __syncthreads();
    if (tid == 0) {
        double lb = 0.0;
#pragma unroll
        for (int e = 0; e < NE; ++e)
            lb += ((double)cnt[e] / (double)(NTOK * 2)) * (red[0][e] / (double)NTOK);
        out_lb[0] = (float)(8.0 * lb);
    }
}

// probe decode (verified on HW in R5): fam0 lane=16k+idx -> val=96+4idx;
// fam1 lane=4idx+k -> val=6+16idx.
__device__ __forceinline__ int dec_idx(double val, int* fam) {
    const double r0 = (val - 96.0) * 0.25;
    const int i0 = (int)r0;
    if ((double)i0 == r0 && i0 >= 0 && i0 < 16) { *fam = 0; return i0; }
    const double r1 = (val - 6.0) * 0.0625;
    const int i1 = (int)r1;
    if ((double)i1 == r1 && i1 >= 0 && i1 < 16) { *fam = 1; return i1; }
    *fam = -1; return 0;
}

struct Frag {
    int vA, kA, uB, kB;   // A-row / A-k / B-col / B-k index of this lane
    int vC[4], uC[4];     // D (row,col) of acc reg r
    int bad;
};

__device__ __forceinline__ Frag probe_layout(int l) {
    Frag fr; fr.bad = 0;
    const d4 zz = {0.0, 0.0, 0.0, 0.0};
    const double dl = (double)l;
    const d4 Dv = __builtin_amdgcn_mfma_f64_16x16x4f64(dl, 1.0, zz, 0, 0, 0);
    const d4 Du = __builtin_amdgcn_mfma_f64_16x16x4f64(1.0, dl, zz, 0, 0, 0);
    int famA = -1, famB = -1;
#pragma unroll
    for (int r = 0; r < 4; ++r) {
        int fa, fb;
        fr.vC[r] = dec_idx(Dv[r], &fa);
        fr.uC[r] = dec_idx(Du[r], &fb);
        if (r == 0) { famA = fa; famB = fb; }
        fr.bad |= (fa != famA) | (fb != famB) | (fa < 0) | (fb < 0);
    }
    fr.vA = (famA == 0) ? (l & 15) : (l >> 2);
    fr.kA = (famA == 0) ? (l >> 4) : (l & 3);
    fr.uB = (famB == 0) ? (l & 15) : (l >> 2);
    fr.kB = (famB == 0) ? (l >> 4) : (l & 3);
    const d4 D3 = __builtin_amdgcn_mfma_f64_16x16x4f64(
        (double)(1 << fr.kA), (double)(16 << fr.kB), zz, 0, 0, 0);
#pragma unroll
    for (int r = 0; r < 4; ++r) fr.bad |= (D3[r] != 1360.0);
    return fr;
}

// gmask row of 32 ushorts per (e, pairIdx, t)
__device__ __forceinline__ size_t gm_row(int e, int pairIdx, int t) {
    return ((size_t)((e << 11) + pairIdx) * 4 + t) * 32;
}

// ---------------------------------------------------------------------------
// Kernel 3a: up projection h = x @ Wup + LIF -> spike bits in gmask.
// R12 config (EF-half split, e=gid&7 XCD-pinned, LDS-staged A) + explicit
// 1-deep B rotate-prefetch (down-R7-proven): next kk's 4 B floats load
// before current kk's 8 MFMAs; B rows are contiguous across kc boundaries
// so the rotate carries across barriers in 4 registers.
// ---------------------------------------------------------------------------
__global__ __launch_bounds__(256, 4) void moe_up(
    const float* __restrict__ x, const float* __restrict__ wup,
    const int* __restrict__ cnt, const int* __restrict__ ltok,
    unsigned short* __restrict__ gmask)
{
    const int gid  = blockIdx.x;
    const int e    = gid & 7;
    const int hf   = (gid >> 3) & 1;
    const int tile = gid >> 4;
    const int c    = cnt[e];
    const int base = tile * TP;
    if (base >= c) return;

    const int tid = threadIdx.x;
    const int w   = tid >> 6;     // wave 0..3
    const int l   = tid & 63;

    __shared__ int    s_tok[TP];
    __shared__ float  xs[32][132];        // staged x rows (row = pair*4+t), 16.9 KB
    __shared__ double dtile[4][16][17];   // per-wave D round-trip, 8.7 KB
    __shared__ int s_bad;

    if (tid < TP) {
        const int idx = base + tid;
        s_tok[tid] = (idx < c) ? ltok[e * NTOK + idx] : ltok[e * NTOK + base];
    }
    if (tid == 0) s_bad = 0;
    __syncthreads();

    const Frag fr = probe_layout(l);
    if (fr.bad) atomicOr(&s_bad, 1);
    __syncthreads();

    if (s_bad) {
        // scalar fallback (dead in practice) — this block's EF-half only
        unsigned short* gm16 = gmask;
        for (int i = tid; i < TP * 4 * 16; i += 256) {   // zero our 16 ushorts/row
            const int pr = i >> 6;
            gm16[gm_row(e, base + pr, (i >> 4) & 3) + hf * 16 + (i & 15)] = 0;
        }
        __syncthreads();
        for (int ci = tid; ci < TP * 256; ci += 256) {
            const int pair = ci >> 8;
            const int f    = hf * 256 + (ci & 255);
            const float* wc = wup + (size_t)e * D_ * EF + f;
            const float* xb = x + (size_t)s_tok[pair] * D_;
            double hh[4] = {0.0, 0.0, 0.0, 0.0};
            for (int d = 0; d < D_; ++d) {
                const double wv = (double)wc[(size_t)d * EF];
#pragma unroll
                for (int t = 0; t < 4; ++t)
                    hh[t] = fma((double)xb[(size_t)t * NTOK * D_ + d], wv, hh[t]);
            }
            double v = 0.0;
#pragma unroll
            for (int t = 0; t < 4; ++t) {
                v = 0.9 * v + hh[t];
                if (v - 1.0 >= 0.0) {
                    v -= 1.0;
                    atomicOr((unsigned*)&gm16[gm_row(e, base + pair, t) + ((f >> 4) & ~1)],
                             1u << (f & 31));
                }
            }
        }
        return;
    }

    // -------- MFMA path --------
    const float* bp = wup + (size_t)e * D_ * EF + (size_t)fr.kB * EF
                    + hf * 256 + w * 64 + fr.uB;

    const d4 zz = {0.0, 0.0, 0.0, 0.0};
    d4 acc0[4], acc1[4];
#pragma unroll
    for (int j = 0; j < 4; ++j) { acc0[j] = zz; acc1[j] = zz; }

    const int arow0 = fr.vA;        // xs row for row-group 0 (pairs 0..3)
    const int arow1 = 16 + fr.vA;   // row-group 1 (pairs 4..7)

    // rotate prologue: current B regs
    float b0c = bp[0], b1c = bp[16], b2c = bp[32], b3c = bp[48];

#pragma unroll 1
    for (int kc = 0; kc < 8; ++kc) {
        __syncthreads();   // previous chunk's readers done
#pragma unroll
        for (int v = 0; v < 4; ++v) {
            const int idx = v * 256 + tid;        // 0..1023 float4 slots
            const int row = idx >> 5;             // 0..31 = pair*4+t
            const int c4  = (idx & 31) << 2;      // 0,4,..,124
            const int pr  = row >> 2, t = row & 3;
            *(float4*)&xs[row][c4] =
                *(const float4*)&x[((size_t)t * NTOK + s_tok[pr]) * D_ + kc * 128 + c4];
        }
        __syncthreads();

#pragma unroll 4
        for (int kk2 = 0; kk2 < 32; ++kk2) {
            const bool glast = (kc == 7) && (kk2 == 31);
            const float* bn = glast ? bp : (bp + (size_t)4 * EF);   // next kk row
            const float nb0 = bn[0], nb1 = bn[16], nb2 = bn[32], nb3 = bn[48];

            const double aD0 = (double)xs[arow0][kk2 * 4 + fr.kA];
            const double aD1 = (double)xs[arow1][kk2 * 4 + fr.kA];
            const double w0 = (double)b0c, w1 = (double)b1c;
            const double w2 = (double)b2c, w3 = (double)b3c;

            acc0[0] = __builtin_amdgcn_mfma_f64_16x16x4f64(aD0, w0, acc0[0], 0, 0, 0);
            acc1[0] = __builtin_amdgcn_mfma_f64_16x16x4f64(aD1, w0, acc1[0], 0, 0, 0);
            acc0[1] = __builtin_amdgcn_mfma_f64_16x16x4f64(aD0, w1, acc0[1], 0, 0, 0);
            acc1[1] = __builtin_amdgcn_mfma_f64_16x16x4f64(aD1, w1, acc1[1], 0, 0, 0);
            acc0[2] = __builtin_amdgcn_mfma_f64_16x16x4f64(aD0, w2, acc0[2], 0, 0, 0);
            acc1[2] = __builtin_amdgcn_mfma_f64_16x16x4f64(aD1, w2, acc1[2], 0, 0, 0);
            acc0[3] = __builtin_amdgcn_mfma_f64_16x16x4f64(aD0, w3, acc0[3], 0, 0, 0);
            acc1[3] = __builtin_amdgcn_mfma_f64_16x16x4f64(aD1, w3, acc1[3], 0, 0, 0);

            b0c = nb0; b1c = nb1; b2c = nb2; b3c = nb3;
            bp = bn;
        }
    }

    // epilogue: per group, per tile: LDS round-trip -> canonical LIF -> gmask
    const int pp = l >> 4;
    const int cc = l & 15;
#pragma unroll
    for (int g = 0; g < 2; ++g) {
#pragma unroll
        for (int j = 0; j < 4; ++j) {
            const d4 av = g ? acc1[j] : acc0[j];
#pragma unroll
            for (int r = 0; r < 4; ++r) dtile[w][fr.vC[r]][fr.uC[r]] = av[r];
            double v = 0.0;
#pragma unroll
            for (int t = 0; t < 4; ++t) {
                v = 0.9 * v + dtile[w][pp * 4 + t][cc];
                const bool s = (v - 1.0 >= 0.0);
                if (s) v -= 1.0;
                const unsigned long long bal = __ballot(s);
                if (l < 4)
                    gmask[gm_row(e, base + g * 4 + l, t) + (hf * 16 + w * 4 + j)] =
                        (unsigned short)(bal >> (l * 16));
            }
        }
    }
}

// ---------------------------------------------------------------------------
// Kernel 3b: down projection — exact R12 config (D-quarter split, e=gid&7
// XCD-pinned, 4 loads : 8 MFMA per kk, acc 32 VGPR, 2048 working blocks).
// ---------------------------------------------------------------------------
__global__ __launch_bounds__(256, 4) void moe_down(
    const float* __restrict__ wdn,
    const int* __restrict__ cnt, const int* __restrict__ ltok,
    const double* __restrict__ lw, const unsigned short* __restrict__ gmask,
    float* __restrict__ out)
{
    const int gid  = blockIdx.x;
    const int e    = gid & 7;
    const int dq   = (gid >> 3) & 3;
    const int tile = gid >> 5;
    const int c    = cnt[e];
    const int base = tile * TP;
    if (base >= c) return;

    const int tid = threadIdx.x;
    const int w   = tid >> 6;
    const int l   = tid & 63;

    __shared__ int    s_tok[TP];
    __shared__ double s_w[TP];
    __shared__ unsigned hm[32][17];       // [pair*4+t][word] spike bits (padded)
    __shared__ double dtile[4][16][17];
    __shared__ int s_bad;

    if (tid < TP) {
        const int idx = base + tid;
        if (idx < c) { s_tok[tid] = ltok[e * NTOK + idx]; s_w[tid] = lw[e * NTOK + idx]; }
        else         { s_tok[tid] = ltok[e * NTOK + base]; s_w[tid] = 0.0; }
    }
    if (tid == 0) s_bad = 0;
    const unsigned* gm32 = (const unsigned*)gmask;
#pragma unroll
    for (int i = tid; i < 32 * 16; i += 256) {
        const int r = i >> 4, wd = i & 15;
        hm[r][wd] = gm32[(gm_row(e, base + (r >> 2), r & 3) >> 1) + wd];
    }
    __syncthreads();

    const Frag fr = probe_layout(l);
    if (fr.bad) atomicOr(&s_bad, 1);
    __syncthreads();

    if (s_bad) {
        // scalar fallback (dead in practice) — this block's d-quarter only
        for (int ci = tid; ci < TP * 256; ci += 256) {
            const int pair = ci >> 8;
            const int d    = dq * 256 + (ci & 255);
            const double wgt2 = s_w[pair];
            const int    nn2  = s_tok[pair];
            const float* wc = wdn + (size_t)e * EF * D_ + d;
            double o[4] = {0.0, 0.0, 0.0, 0.0};
            for (int f = 0; f < EF; ++f) {
                const double wv = (double)wc[(size_t)f * D_];
#pragma unroll
                for (int t = 0; t < 4; ++t)
                    if ((hm[pair * 4 + t][f >> 5] >> (f & 31)) & 1) o[t] += wv;
            }
            double v = 0.0;
#pragma unroll
            for (int t = 0; t < 4; ++t) {
                v = 0.9 * v + o[t];
                if (v - 1.0 >= 0.0) {
                    v -= 1.0;
                    if (wgt2 != 0.0)
                        atomicAdd(&out[((size_t)t * NTOK + nn2) * D_ + d], (float)wgt2);
                }
            }
        }
        return;
    }

    // -------- MFMA path (single d-quarter) --------
    const d4 zz = {0.0, 0.0, 0.0, 0.0};
    const int pp = l >> 4;
    const int cc = l & 15;

    const float* dp = wdn + (size_t)e * EF * D_ + (size_t)fr.kB * D_
                    + dq * 256 + w * 64 + fr.uB;

    d4 acc0[4], acc1[4];
#pragma unroll
    for (int j = 0; j < 4; ++j) { acc0[j] = zz; acc1[j] = zz; }

    float bC[4];
#pragma unroll
    for (int j = 0; j < 4; ++j) bC[j] = dp[j * 16];
    unsigned m0 = hm[fr.vA][0];
    unsigned m1 = hm[16 + fr.vA][0];

#pragma unroll 1
    for (int wd = 0; wd < 16; ++wd) {
        const unsigned cm0 = m0, cm1 = m1;
        const int nw = (wd < 15) ? (wd + 1) : wd;
        m0 = hm[fr.vA][nw];              // prefetch next word's masks
        m1 = hm[16 + fr.vA][nw];
#pragma unroll
        for (int k2 = 0; k2 < 8; ++k2) {
            const bool last = (wd == 15) && (k2 == 7);
            const float* dn_ = last ? dp : (dp + (size_t)4 * D_);
            float bN[4];
#pragma unroll
            for (int j = 0; j < 4; ++j) bN[j] = dn_[j * 16];   // prefetch next kk

            const int bit = k2 * 4 + fr.kA;
            const double aD0 = ((cm0 >> bit) & 1u) ? 1.0 : 0.0;
            const double aD1 = ((cm1 >> bit) & 1u) ? 1.0 : 0.0;
#pragma unroll
            for (int j = 0; j < 4; ++j) {
                const double bD = (double)bC[j];
                acc0[j] = __builtin_amdgcn_mfma_f64_16x16x4f64(aD0, bD, acc0[j], 0, 0, 0);
                acc1[j] = __builtin_amdgcn_mfma_f64_16x16x4f64(aD1, bD, acc1[j], 0, 0, 0);
            }
#pragma unroll
            for (int j = 0; j < 4; ++j) bC[j] = bN[j];
            dp = dn_;
        }
    }

    // epilogue: round-trip -> canonical LIF -> weighted spike scatter
#pragma unroll
    for (int g = 0; g < 2; ++g) {
        const int pair = g * 4 + pp;
        const double wgt = s_w[pair];
        const int    nn  = s_tok[pair];
#pragma unroll
        for (int j = 0; j < 4; ++j) {
            const d4 av = g ? acc1[j] : acc0[j];
#pragma unroll
            for (int r = 0; r < 4; ++r) dtile[w][fr.vC[r]][fr.uC[r]] = av[r];
            const int d = dq * 256 + w * 64 + j * 16 + cc;
            double v = 0.0;
#pragma unroll
            for (int t = 0; t < 4; ++t) {
                v = 0.9 * v + dtile[w][pp * 4 + t][cc];
                if (v - 1.0 >= 0.0) {
                    v -= 1.0;
                    if (wgt != 0.0)
                        atomicAdd(&out[((size_t)t * NTOK + nn) * D_ + d], (float)wgt);
                }
            }
        }
    }
}

// ---------------------------------------------------------------------------
extern "C" void kernel_launch(void* const* d_in, const int* in_sizes, int n_in,
                              void* d_out, int out_size, void* d_ws, size_t ws_size,
                              hipStream_t stream)
{
    const float* x    = (const float*)d_in[0];
    const float* wup  = (const float*)d_in[1];
    const float* wdn  = (const float*)d_in[2];
    const float* bias = (const float*)d_in[3];
    float* out = (float*)d_out;
    char*  ws  = (char*)d_ws;

    double* rp   = (double*)(ws + WS_RP);
    int*    cnt  = (int*)(ws + WS_CNT);
    int*    ltok = (int*)(ws + WS_LTOK);
    double* lw   = (double*)(ws + WS_LW);
    unsigned short* gmask = (unsigned short*)(ws + WS_GMASK);

    hipMemsetAsync(d_out, 0, (size_t)out_size * sizeof(float), stream);
    hipMemsetAsync(cnt, 0, NE * sizeof(int), stream);

    moe_routing<<<NTOK, 256, 0, stream>>>(x, bias, rp, cnt, ltok, lw);
    moe_finalize<<<1, 256, 0, stream>>>(rp, cnt, out + (size_t)T_ * NTOK * D_);
    moe_up<<<NE * 1024, 256, 0, stream>>>(x, wup, cnt, ltok, gmask);
    moe_down<<<NE * 1024, 256, 0, stream>>>(wdn, cnt, ltok, lw, gmask, out);
}